// Round 1
// baseline (93.743 us; speedup 1.0000x reference)
//
#include <hip/hip_runtime.h>

namespace {
constexpr int Bsz = 512;
constexpr int N   = 64;
constexpr int D   = 32;
constexpr int PD  = 36;   // padded row (floats): 144 B rows -> 16B-aligned float4 reads

// gate[i][j] = 1[ ind0[i,:] . ind1[j,:] > 0 ]
__global__ void gate_kernel(const float* __restrict__ ind, float* __restrict__ gate) {
    int i = blockIdx.x;
    int j = threadIdx.x;
    const float* u = ind + 0 * N * D + i * D;
    const float* v = ind + 1 * N * D + j * D;
    float acc = 0.f;
#pragma unroll
    for (int d = 0; d < D; ++d) acc += u[d] * v[d];
    gate[i * N + j] = (acc > 0.f) ? 1.f : 0.f;
}

// elu(x)+1 == exp(min(x,0)) + max(x,0)   (branchless, 1 transcendental)
__device__ __forceinline__ float elup1(float x) {
    return __expf(fminf(x, 0.f)) + fmaxf(x, 0.f);
}

__global__ __launch_bounds__(512, 4) void fused_kernel(
        const float* __restrict__ feature,
        const float* __restrict__ ind,
        const float* __restrict__ gate,
        float* __restrict__ out) {
    __shared__ float ind_lds[3][N][PD];
    __shared__ float feat_lds[N][PD];
    __shared__ float s_lds[3][N];

    const int b    = blockIdx.x;
    const int t    = threadIdx.x;
    const int lane = t & 63;
    const int wave = t >> 6;

    // ---- stage indicator (1536 float4) and feature tile (512 float4) ----
    {
        const float4* src = reinterpret_cast<const float4*>(ind);
#pragma unroll
        for (int f4 = t; f4 < 3 * N * D / 4; f4 += 512) {
            int a = f4 / (N * D / 4);
            int r = f4 % (N * D / 4);
            int n = r / (D / 4);
            int k = r % (D / 4);
            *reinterpret_cast<float4*>(&ind_lds[a][n][k * 4]) = src[f4];
        }
        const float4* fsrc = reinterpret_cast<const float4*>(feature + (size_t)b * N * D);
        if (t < N * D / 4) {
            int n = t / (D / 4);
            int k = t % (D / 4);
            *reinterpret_cast<float4*>(&feat_lds[n][k * 4]) = fsrc[t];
        }
    }
    __syncthreads();

    // ---- s[a][n] = feature[b,n,:] . ind[a,n,:] ----
    if (t < 3 * N) {
        int a = t >> 6, n = t & 63;
        float acc = 0.f;
#pragma unroll
        for (int d = 0; d < D; ++d) acc += feat_lds[n][d] * ind_lds[a][n][d];
        s_lds[a][n] = acc;
    }
    __syncthreads();

    const int   j   = lane;
    const float s1j = s_lds[1][j];

#pragma unroll 1
    for (int r = 0; r < 8; ++r) {
        const int   i   = wave * 8 + r;
        const float s0i = s_lds[0][i];

        // score_j = sum_d elup1(s0_i * ind0[j,d]) * elup1(s1_j * ind1[i,d])
        float score = 0.f;
#pragma unroll
        for (int k = 0; k < D / 4; ++k) {
            float4 u4 = *reinterpret_cast<const float4*>(&ind_lds[0][j][k * 4]);
            float4 v4 = *reinterpret_cast<const float4*>(&ind_lds[1][i][k * 4]);
            float uu[4] = {u4.x, u4.y, u4.z, u4.w};
            float vv[4] = {v4.x, v4.y, v4.z, v4.w};
#pragma unroll
            for (int c = 0; c < 4; ++c) {
                float q  = elup1(s0i * uu[c]);
                float kt = elup1(s1j * vv[c]);
                score += q * kt;
            }
        }

        // wave-wide softmax over j (64 lanes)
        float m = score;
#pragma unroll
        for (int off = 32; off >= 1; off >>= 1) m = fmaxf(m, __shfl_xor(m, off));
        float e = __expf(score - m);
        float ssum = e;
#pragma unroll
        for (int off = 32; off >= 1; off >>= 1) ssum += __shfl_xor(ssum, off);

        float sh = (e / ssum) * gate[i * N + j];

        // out[b,i,d] = s2[i] * sum_j sh_j * ind2[j,d]
        // lanes 0..31 accumulate j in [0,32), lanes 32..63 accumulate j in [32,64)
        const int d    = lane & 31;
        const int half = lane >> 5;
        float acc = 0.f;
#pragma unroll
        for (int jj = 0; jj < 32; ++jj) {
            int   jidx = half * 32 + jj;
            float shv  = __shfl(sh, jidx);
            acc += shv * ind_lds[2][jidx][d];
        }
        acc += __shfl_xor(acc, 32);
        if (half == 0) {
            out[((size_t)b * N + i) * D + d] = s_lds[2][i] * acc;
        }
    }
}
}  // namespace

extern "C" void kernel_launch(void* const* d_in, const int* in_sizes, int n_in,
                              void* d_out, int out_size, void* d_ws, size_t ws_size,
                              hipStream_t stream) {
    const float* feature = (const float*)d_in[0];
    const float* ind     = (const float*)d_in[1];
    float*       gate    = (float*)d_ws;   // N*N floats = 16 KB scratch
    float*       out     = (float*)d_out;

    gate_kernel<<<N, N, 0, stream>>>(ind, gate);
    fused_kernel<<<Bsz, 512, 0, stream>>>(feature, ind, gate, out);
}

// Round 2
// 88.808 us; speedup vs baseline: 1.0556x; 1.0556x over previous
//
#include <hip/hip_runtime.h>

namespace {
constexpr int N  = 64;
constexpr int D  = 32;
constexpr int PD = 36;   // padded ind row (dwords): stride 36 measured conflict-free (round 1)
constexpr int SHP = 68;  // sh row pad (dwords), float4-aligned
constexpr float LOG2E = 1.4426950408889634f;
constexpr float LN2   = 0.6931471805599453f;

#if __has_builtin(__builtin_amdgcn_exp2f)
__device__ __forceinline__ float fexp2(float x) { return __builtin_amdgcn_exp2f(x); }
#else
__device__ __forceinline__ float fexp2(float x) { return exp2f(x); }
#endif
#if __has_builtin(__builtin_amdgcn_rcpf)
__device__ __forceinline__ float frcp(float x) { return __builtin_amdgcn_rcpf(x); }
#else
__device__ __forceinline__ float frcp(float x) { return 1.0f / x; }
#endif

// elu(x)+1 == exp(min(x,0)) + max(x,0).  With xL = x*log2e pre-scaled:
//   = exp2(min(xL,0)) + max(xL,0)*ln2   -> mul,min,exp2,max,fma = 5 ops
__device__ __forceinline__ float elup1_scaled(float xL) {
    return fmaf(fmaxf(xL, 0.f), LN2, fexp2(fminf(xL, 0.f)));
}

// One kernel, grid = 1024 (2 blocks per b, each owns 32 i-rows), block = 512 (8 waves).
// Phases: stage ind -> {gate rows, s=feature.ind} -> score+softmax (lane=j, wave owns
// 4 rows, u=ind0[lane,:] in regs, v=ind1[i,:] broadcast) -> block GEMM sh @ ind2.
__global__ __launch_bounds__(512, 6) void fused(
        const float* __restrict__ feature,
        const float* __restrict__ ind,
        float* __restrict__ out) {
    __shared__ float ind_lds[3][N][PD];   // 27648 B
    __shared__ float s_lds[3][N];         //   768 B
    __shared__ float gate_lds[32][N];     //  8192 B
    __shared__ float sh_lds[32][SHP];     //  8704 B   (total ~45.3 KB -> 3 blocks/CU)

    const int t    = threadIdx.x;
    const int lane = t & 63;
    const int wave = t >> 6;
    const int blk  = blockIdx.x;
    const int b    = blk >> 1;
    const int i_base = (blk & 1) * 32;

    // ---- stage indicator: 1536 float4, 3 per thread, coalesced ----
    {
        const float4* src = reinterpret_cast<const float4*>(ind);
#pragma unroll
        for (int idx = t; idx < 3 * N * D / 4; idx += 512) {
            int a = idx >> 9;
            int r = idx & 511;
            int n = r >> 3;
            int k = r & 7;
            *reinterpret_cast<float4*>(&ind_lds[a][n][k * 4]) = src[idx];
        }
    }
    __syncthreads();

    // ---- phase 1: gate rows (all threads, 4 dots each) + s (threads<192) ----
    {
        const int i_loc = t >> 4;        // [0,32)
        const int jq    = t & 15;        // j in {jq, jq+16, jq+32, jq+48} (consecutive-row reads)
        float4 acc = {0.f, 0.f, 0.f, 0.f};
#pragma unroll
        for (int dq = 0; dq < 8; ++dq) {
            float4 a4 = *reinterpret_cast<const float4*>(&ind_lds[0][i_base + i_loc][dq * 4]);
#pragma unroll
            for (int c = 0; c < 4; ++c) {
                float4 b4 = *reinterpret_cast<const float4*>(&ind_lds[1][jq + 16 * c][dq * 4]);
                (&acc.x)[c] += a4.x * b4.x + a4.y * b4.y + a4.z * b4.z + a4.w * b4.w;
            }
        }
#pragma unroll
        for (int c = 0; c < 4; ++c)
            gate_lds[i_loc][jq + 16 * c] = ((&acc.x)[c] > 0.f) ? 1.f : 0.f;

        if (t < 3 * N) {
            int a = t >> 6, n = t & 63;
            const float4* frow = reinterpret_cast<const float4*>(feature + ((size_t)b * N + n) * D);
            float sa = 0.f;
#pragma unroll
            for (int k = 0; k < 8; ++k) {
                float4 f4 = frow[k];
                float4 i4 = *reinterpret_cast<const float4*>(&ind_lds[a][n][k * 4]);
                sa += f4.x * i4.x + f4.y * i4.y + f4.z * i4.z + f4.w * i4.w;
            }
            s_lds[a][n] = sa;
        }
    }
    __syncthreads();

    // ---- per-lane registers: u = ind0[lane,:] (32 VGPRs), s1 scaled ----
    float4 u[8];
#pragma unroll
    for (int k = 0; k < 8; ++k)
        u[k] = *reinterpret_cast<const float4*>(&ind_lds[0][lane][k * 4]);
    const float s1jL = s_lds[1][lane] * LOG2E;

    // ---- score + softmax: wave owns rows i_loc = wave*4 .. +3, lane = j ----
#pragma unroll 1
    for (int r = 0; r < 4; ++r) {
        const int   i_loc = wave * 4 + r;
        const int   ig    = i_base + i_loc;
        const float s0iL  = s_lds[0][ig] * LOG2E;
        const float s2i   = s_lds[2][ig];

        float score = 0.f;
#pragma unroll
        for (int k = 0; k < 8; ++k) {
            float4 v4 = *reinterpret_cast<const float4*>(&ind_lds[1][ig][k * 4]);  // broadcast
#pragma unroll
            for (int c = 0; c < 4; ++c) {
                float q  = elup1_scaled(s0iL * (&u[k].x)[c]);
                float kt = elup1_scaled(s1jL * (&v4.x)[c]);
                score = fmaf(q, kt, score);
            }
        }

        float m = score;
#pragma unroll
        for (int off = 32; off >= 1; off >>= 1) m = fmaxf(m, __shfl_xor(m, off));
        float e = fexp2((score - m) * LOG2E);
        float ssum = e;
#pragma unroll
        for (int off = 32; off >= 1; off >>= 1) ssum += __shfl_xor(ssum, off);

        float g   = gate_lds[i_loc][lane];
        float shv = (e * g) * (frcp(ssum) * s2i);   // fold gate, 1/sum, s2[i]
        sh_lds[i_loc][lane] = shv;
    }
    __syncthreads();

    // ---- phase 2: out[i,:] = sh[i,:] @ ind2, thread = (i, d-quad, j-half) ----
    {
        const int i_loc = t >> 4;
        const int sub   = t & 15;
        const int dq    = sub & 7;
        const int jh    = sub >> 3;
        float4 acc = {0.f, 0.f, 0.f, 0.f};
#pragma unroll
        for (int jj = 0; jj < 32; jj += 4) {
            int j = jh * 32 + jj;
            float4 sh4 = *reinterpret_cast<const float4*>(&sh_lds[i_loc][j]);
#pragma unroll
            for (int c = 0; c < 4; ++c) {
                float4 v4 = *reinterpret_cast<const float4*>(&ind_lds[2][j + c][dq * 4]);
                float  w  = (&sh4.x)[c];
                acc.x = fmaf(w, v4.x, acc.x);
                acc.y = fmaf(w, v4.y, acc.y);
                acc.z = fmaf(w, v4.z, acc.z);
                acc.w = fmaf(w, v4.w, acc.w);
            }
        }
        acc.x += __shfl_xor(acc.x, 8);   // combine j-halves (lanes t, t^8)
        acc.y += __shfl_xor(acc.y, 8);
        acc.z += __shfl_xor(acc.z, 8);
        acc.w += __shfl_xor(acc.w, 8);
        if (jh == 0) {
            *reinterpret_cast<float4*>(out + ((size_t)b * N + i_base + i_loc) * D + dq * 4) = acc;
        }
    }
}
}  // namespace

extern "C" void kernel_launch(void* const* d_in, const int* in_sizes, int n_in,
                              void* d_out, int out_size, void* d_ws, size_t ws_size,
                              hipStream_t stream) {
    const float* feature = (const float*)d_in[0];
    const float* ind     = (const float*)d_in[1];
    float*       out     = (float*)d_out;
    fused<<<1024, 512, 0, stream>>>(feature, ind, out);
}